// Round 1
// 252.045 us; speedup vs baseline: 1.1405x; 1.1405x over previous
//
#include <hip/hip_runtime.h>
#include <hip/hip_bf16.h>
#include <cstdint>

// B=8, N=1024, D=1024, H=16, hd=64, scale=1/8.
// Facts: inputs fp32, output fp32, ws = 64 MiB, threshold 1.47e-3 (bf16
// intermediates give 4.9e-4 — R6/R7 verified). R7 swizzled-LDS GEMM verified
// on HW (0 bank conflicts, correct). R8: A pre-converted to bf16 (d_out as
// scratch), softmax without max-subtraction (shift-invariant; scores |s|<~3).
// R9: attention rewritten on 32x32x16 MFMA with swapped QK^T (S^T), so each
// lane holds a full P-row slice -> in-register P redistribution via
// v_cvt_pk_bf16_f32 + permlane32_swap (T12). No Ps LDS round-trip, no scalar
// ds_write_b16, row-sum is lane-local (single shfl_xor(32) at the end).
// 32 q-rows/wave (128/block), grid (h,qt,b) so a head's q-tiles share an XCD.

typedef __attribute__((ext_vector_type(8))) short short8;   // 8 bf16
typedef __attribute__((ext_vector_type(4))) float floatx4;  // 16x16 MFMA acc
typedef __attribute__((ext_vector_type(16))) float f32x16;  // 32x32 MFMA acc
typedef __attribute__((ext_vector_type(2))) unsigned int uint2v;

__device__ __forceinline__ ushort f2bf(float f) {
    union { float f; uint32_t i; } v; v.f = f;
    uint32_t r = v.i + 0x7fffu + ((v.i >> 16) & 1u);  // RNE
    return (ushort)(r >> 16);
}
__device__ __forceinline__ uint32_t pack2(float a, float b) {
    return (uint32_t)f2bf(a) | ((uint32_t)f2bf(b) << 16);
}
__device__ __forceinline__ uint32_t cvtpk_bf16(float a, float b) {
    uint32_t r;
    asm("v_cvt_pk_bf16_f32 %0, %1, %2" : "=v"(r) : "v"(a), "v"(b));
    return r;  // low16 = bf16(a), high16 = bf16(b)
}
__device__ __forceinline__ void gl2lds16(const void* g, void* lds) {
    __builtin_amdgcn_global_load_lds(
        (const __attribute__((address_space(1))) uint32_t*)(uintptr_t)g,
        (__attribute__((address_space(3))) uint32_t*)(uintptr_t)lds,
        16, 0, 0);
}

// ---------------------------------------------------------------------------
// A prep: fp32 -> bf16, contiguous. 8 floats/thread.
// ---------------------------------------------------------------------------
__global__ __launch_bounds__(256)
void aprep(const float* __restrict__ in, ushort* __restrict__ ob) {
    const int i = (blockIdx.x * 256 + threadIdx.x) * 8;
    const float4 f0 = *(const float4*)&in[i];
    const float4 f1 = *(const float4*)&in[i + 4];
    uint4 pk;
    pk.x = pack2(f0.x, f0.y); pk.y = pack2(f0.z, f0.w);
    pk.z = pack2(f1.x, f1.y); pk.w = pack2(f1.z, f1.w);
    *(uint4*)&ob[i] = pk;
}

// ---------------------------------------------------------------------------
// Weight prep: W fp32 [K,N] -> WT bf16 [N,K].
// ---------------------------------------------------------------------------
__global__ __launch_bounds__(256)
void wprep(const float* __restrict__ W, ushort* __restrict__ WT,
           int K, int N) {
    __shared__ ushort T[64 * 72];
    const int tid = threadIdx.x;
    const int k0 = blockIdx.y * 64, n0 = blockIdx.x * 64;
#pragma unroll
    for (int i = 0; i < 4; ++i) {
        int c = tid + i * 256;
        int kl = c >> 4, n4 = (c & 15) << 2;
        const float4 f = *(const float4*)&W[(size_t)(k0 + kl) * N + n0 + n4];
        T[(n4 + 0) * 72 + kl] = f2bf(f.x);
        T[(n4 + 1) * 72 + kl] = f2bf(f.y);
        T[(n4 + 2) * 72 + kl] = f2bf(f.z);
        T[(n4 + 3) * 72 + kl] = f2bf(f.w);
    }
    __syncthreads();
#pragma unroll
    for (int i = 0; i < 2; ++i) {
        int c = tid + i * 256;
        int nl = c >> 3, k8 = (c & 7) << 3;
        *(uint4*)&WT[(size_t)(n0 + nl) * K + k0 + k8] =
            *(const uint4*)&T[nl * 72 + k8];
    }
}

// ---------------------------------------------------------------------------
// BT-GEMM (all-bf16): C[M,N] = A[M,K]*BT[N,K]^T + bias[N]. BM=BN=128, BK=64.
// Swizzled unpadded LDS (R7 HW-verified: 0 conflicts). Dual global_load_lds.
// MODE 0: row-major OutT store. MODE 1: QKV scatter (V transposed).
// ---------------------------------------------------------------------------
template <int MODE, typename OutT>
__global__ __launch_bounds__(256)
void gemm_bt(const ushort* __restrict__ A, const ushort* __restrict__ BT,
             const float* __restrict__ bias, OutT* __restrict__ C,
             ushort* __restrict__ qb, ushort* __restrict__ kb,
             ushort* __restrict__ vb, int M, int Nn, int K) {
    __shared__ ushort As[128 * 64];
    __shared__ ushort Bs[128 * 64];
    const int tid = threadIdx.x;
    const int lane = tid & 63, w = tid >> 6;
    const int wm = w & 1, wn = w >> 1;
    const int l16 = lane & 15, quad = lane >> 4;
    const int m0 = blockIdx.y * 128, n0 = blockIdx.x * 128;
    const int srow = lane >> 3;
    const int cg = (lane & 7) ^ srow;
    const int sx = l16 & 7;

    floatx4 acc[4][4];
#pragma unroll
    for (int i = 0; i < 4; ++i)
#pragma unroll
        for (int j = 0; j < 4; ++j) acc[i][j] = (floatx4)0.f;

    const int nkt = K >> 6;
    for (int kt = 0; kt < nkt; ++kt) {
        __syncthreads();
#pragma unroll
        for (int i = 0; i < 4; ++i) {
            const int row = w * 32 + i * 8 + srow;
            gl2lds16(&BT[(size_t)(n0 + row) * K + kt * 64 + cg * 8],
                     &Bs[(w * 32 + i * 8) * 64]);
            gl2lds16(&A[(size_t)(m0 + row) * K + kt * 64 + cg * 8],
                     &As[(w * 32 + i * 8) * 64]);
        }
        __syncthreads();
#pragma unroll
        for (int kk = 0; kk < 2; ++kk) {
            const int sl = ((kk << 2) | quad) ^ sx;
            short8 af[4], bfr[4];
#pragma unroll
            for (int mi = 0; mi < 4; ++mi)
                af[mi] = *(const short8*)&As[(wm * 64 + mi * 16 + l16) * 64 +
                                             sl * 8];
#pragma unroll
            for (int ni = 0; ni < 4; ++ni)
                bfr[ni] = *(const short8*)&Bs[(wn * 64 + ni * 16 + l16) * 64 +
                                              sl * 8];
#pragma unroll
            for (int mi = 0; mi < 4; ++mi)
#pragma unroll
                for (int ni = 0; ni < 4; ++ni)
                    acc[mi][ni] = __builtin_amdgcn_mfma_f32_16x16x32_bf16(
                        af[mi], bfr[ni], acc[mi][ni], 0, 0, 0);
        }
    }

#pragma unroll
    for (int mi = 0; mi < 4; ++mi) {
#pragma unroll
        for (int ni = 0; ni < 4; ++ni) {
            const int jg = n0 + wn * 64 + ni * 16 + l16;
            const float bv = bias[jg];
#pragma unroll
            for (int r = 0; r < 4; ++r) {
                const int mg = m0 + wm * 64 + mi * 16 + quad * 4 + r;
                const float vout = acc[mi][ni][r] + bv;
                if (MODE == 0) {
                    if (sizeof(OutT) == 4)
                        ((float*)C)[(size_t)mg * Nn + jg] = vout;
                    else
                        ((ushort*)C)[(size_t)mg * Nn + jg] = f2bf(vout);
                } else {
                    const int which = jg >> 10;
                    const int h = (jg & 1023) >> 6;
                    const int d = jg & 63;
                    const int bb = mg >> 10, nn = mg & 1023;
                    if (which == 0)
                        qb[(size_t)((bb * 16 + h) * 1024 + nn) * 64 + d] =
                            f2bf(vout);
                    else if (which == 1)
                        kb[(size_t)((bb * 16 + h) * 1024 + nn) * 64 + d] =
                            f2bf(vout);
                    else  // V pre-transposed: [B,H,hd,N]
                        vb[((size_t)(bb * 16 + h) * 64 + d) * 1024 + nn] =
                            f2bf(vout);
                }
            }
        }
    }
}

// ---------------------------------------------------------------------------
// Flash attention, 32x32x16 MFMA, swapped QK^T (S^T: col=q, row=key).
// q,k: [B,H,N,hd]; v: [B,H,hd,N]; o: [B,N,H*hd] bf16.
// Per wave: 32 q-rows. Per 32-key subtile: 4 MFMA QK^T, exp2 in f32 regs,
// P -> bf16 via v_cvt_pk_bf16_f32 pairs, permlane32_swap redistributes to
// PV A-fragment layout (k = hi*8 + j) with zero LDS traffic. Row-sum `ls`
// is lane-local (q = lane&31); one shfl_xor(32) merges the hi halves.
// ---------------------------------------------------------------------------
__global__ __launch_bounds__(256, 4)
void attn_kernel(const ushort* __restrict__ q, const ushort* __restrict__ k,
                 const ushort* __restrict__ v, ushort* __restrict__ o) {
    __shared__ ushort Qs[128 * 64];
    __shared__ ushort Ks[64 * 64];
    __shared__ ushort VTs[64 * 64];      // VT[d][key]
    const int tid = threadIdx.x;
    const int lane = tid & 63, w = tid >> 6;
    const int l31 = lane & 31, hi = lane >> 5, l7 = lane & 7;
    const int h = blockIdx.x, qt = blockIdx.y, b = blockIdx.z;  // h fastest:
    // linear id = h + 16*qt + 128*b -> all 8 q-tiles of a head land on the
    // same XCD (id mod 8 == h&7); per-XCD K/V working set = 16 heads * 256KB
    // = 4 MB = one L2.
    const size_t head_off = (size_t)(b * 16 + h) * 1024 * 64;
    const ushort* Qp = q + head_off + (size_t)qt * 128 * 64;
    const ushort* Vp = v + head_off;     // [64 d][1024 key]
    const int srow = lane >> 3;
    const int cg = (lane & 7) ^ srow;
    const float CEXP = 0.125f * 1.44269504f;  // scale * log2(e)

    // Q: 128 rows, 32/wave, swizzled dest via pre-swizzled source granule
#pragma unroll
    for (int g = 0; g < 4; ++g)
        gl2lds16(&Qp[(size_t)(w * 32 + g * 8 + srow) * 64 + cg * 8],
                 &Qs[(w * 32 + g * 8) * 64]);
    __syncthreads();

    // Q fragment (B-operand of swapped QK^T): col=q=lane&31, k=hd c*16+hi*8+j
    short8 bq[4];
#pragma unroll
    for (int c = 0; c < 4; ++c)
        bq[c] = *(const short8*)&Qs[(w * 32 + l31) * 64 +
                                    ((2 * c + hi) ^ l7) * 8];

    f32x16 oacc[2];
    oacc[0] = (f32x16)0.f;
    oacc[1] = (f32x16)0.f;
    float ls = 0.f;

    for (int kt = 0; kt < 16; ++kt) {
        __syncthreads();
        const ushort* Kp = k + head_off + (size_t)kt * 64 * 64;
#pragma unroll
        for (int g = 0; g < 2; ++g) {
            gl2lds16(&Kp[(size_t)(w * 16 + g * 8 + srow) * 64 + cg * 8],
                     &Ks[(w * 16 + g * 8) * 64]);
            gl2lds16(&Vp[(size_t)(w * 16 + g * 8 + srow) * 1024 +
                         kt * 64 + cg * 8],
                     &VTs[(w * 16 + g * 8) * 64]);
        }
        __syncthreads();

#pragma unroll
        for (int st = 0; st < 2; ++st) {
            // S^T = K_st * Q^T : A=K rows (key), B=Q rows (q)
            f32x16 sacc = (f32x16)0.f;
#pragma unroll
            for (int c = 0; c < 4; ++c) {
                short8 ak = *(const short8*)&Ks[(st * 32 + l31) * 64 +
                                                ((2 * c + hi) ^ l7) * 8];
                sacc = __builtin_amdgcn_mfma_f32_32x32x16_bf16(
                    ak, bq[c], sacc, 0, 0, 0);
            }
            // sacc[r] = S[key = st*32 + (r&3)+8*(r>>2)+4*hi][q = w*32+l31]
            // p = 2^(s*c); lane-local row partial sum; pack pairs to bf16.
            uint32_t wd[8];
#pragma unroll
            for (int i = 0; i < 8; ++i) {
                const float e0 = __builtin_amdgcn_exp2f(sacc[2 * i] * CEXP);
                const float e1 = __builtin_amdgcn_exp2f(sacc[2 * i + 1] * CEXP);
                ls += e0 + e1;
                wd[i] = cvtpk_bf16(e0, e1);  // keys {base, base+1}
            }
            // wd[i] keys: 8*(i>>1) + 2*(i&1) + 4*hi + {0,1}.
            // permlane32_swap(vdst,vsrc): vdst.hi <-> vsrc.lo =>
            //   ret[0] = {vdst.lo, vsrc.lo}, ret[1] = {vdst.hi, vsrc.hi}.
            // swap(w0,w2): ret[0] = A-frag word j=0, ret[1] = word j=2, etc.
            short8 ap[2];
#pragma unroll
            for (int c2 = 0; c2 < 2; ++c2) {
                uint2v sA = __builtin_amdgcn_permlane32_swap(
                    wd[4 * c2 + 0], wd[4 * c2 + 2], false, false);
                uint2v sB = __builtin_amdgcn_permlane32_swap(
                    wd[4 * c2 + 1], wd[4 * c2 + 3], false, false);
                union { uint32_t u[4]; short8 s; } t;
                t.u[0] = sA[0]; t.u[1] = sB[0];
                t.u[2] = sA[1]; t.u[3] = sB[1];
                ap[c2] = t.s;  // A[row=q=l31][k = c2*16 + hi*8 + j]
            }
            // O += P V : B = VT rows (d), k = key
#pragma unroll
            for (int dt = 0; dt < 2; ++dt)
#pragma unroll
                for (int c2 = 0; c2 < 2; ++c2) {
                    short8 bv = *(const short8*)&VTs[
                        (dt * 32 + l31) * 64 +
                        ((st * 4 + c2 * 2 + hi) ^ l7) * 8];
                    oacc[dt] = __builtin_amdgcn_mfma_f32_32x32x16_bf16(
                        ap[c2], bv, oacc[dt], 0, 0, 0);
                }
        }
    }

    // merge hi-half partial sums: each lane then holds full sum for q=l31
    ls += __shfl_xor(ls, 32, 64);
    const float inv = 1.f / ls;

    // oacc[dt][r]: O[q = w*32 + (r&3)+8*(r>>2)+4*hi][d = dt*32 + l31]
#pragma unroll
    for (int r = 0; r < 16; ++r) {
        const int qout = (r & 3) + ((r >> 2) << 3) + (hi << 2);
        const float iq = __shfl(inv, qout, 64);
        const int n = qt * 128 + w * 32 + qout;
#pragma unroll
        for (int dt = 0; dt < 2; ++dt)
            o[((size_t)(b * 1024 + n)) * 1024 + h * 64 + dt * 32 + l31] =
                f2bf(oacc[dt][r] * iq);
    }
}

// ---------------------------------------------------------------------------
extern "C" void kernel_launch(void* const* d_in, const int* in_sizes, int n_in,
                              void* d_out, int out_size, void* d_ws,
                              size_t ws_size, hipStream_t stream) {
    const void *inp = d_in[0], *w_qkv = d_in[1], *b_qkv = d_in[2],
               *w_proj = d_in[3], *b_proj = d_in[4];
    for (int i = 0; i < n_in; ++i) {
        switch (in_sizes[i]) {
            case 8 * 1024 * 1024: inp    = d_in[i]; break;
            case 3 * 1024 * 1024: w_qkv  = d_in[i]; break;
            case 3072:            b_qkv  = d_in[i]; break;
            case 1024 * 1024:     w_proj = d_in[i]; break;
            case 1024:            b_proj = d_in[i]; break;
        }
    }
    float* out = (float*)d_out;

    // ws (64 MiB): [0,16M) qb -> later wprojT; [16,32M) kb; [32,48M) vbT;
    // [48,64M) ob, whose first 6.3 MB first hosts wqkvT (dead before attn).
    // d_out (32 MB fp32): first 16.8 MB used as bf16-A scratch until the
    // final proj GEMM overwrites all of d_out (proj reads only ws).
    char* ws = (char*)d_ws;
    ushort* qb  = (ushort*)(ws);
    ushort* kb  = (ushort*)(ws + (size_t)16 * 1024 * 1024);
    ushort* vbT = (ushort*)(ws + (size_t)32 * 1024 * 1024);
    ushort* ob  = (ushort*)(ws + (size_t)48 * 1024 * 1024);
    ushort* wqkvT  = ob;
    ushort* wprojT = qb;
    ushort* abf = (ushort*)d_out;   // 16.8 MB bf16 scratch inside d_out

    // t0: inp fp32 -> bf16 (d_out scratch); w_qkv -> wqkvT
    aprep<<<8 * 1024 * 1024 / (256 * 8), 256, 0, stream>>>(
        (const float*)inp, abf);
    wprep<<<dim3(3072 / 64, 1024 / 64), 256, 0, stream>>>(
        (const float*)w_qkv, wqkvT, 1024, 3072);

    // t1: QKV GEMM (all-bf16, dual global_load_lds) -> scatter q/k/vT
    gemm_bt<1, ushort><<<dim3(3072 / 128, 8192 / 128), 256, 0, stream>>>(
        abf, wqkvT, (const float*)b_qkv, (ushort*)nullptr, qb, kb, vbT,
        8192, 3072, 1024);

    // t2: attention — grid (h, qt, b): head-major for XCD/L2 locality
    attn_kernel<<<dim3(16, 8, 8), 256, 0, stream>>>(qb, kb, vbT, ob);

    // t2.5: w_proj -> wprojT (into dead qb region)
    wprep<<<dim3(1024 / 64, 1024 / 64), 256, 0, stream>>>(
        (const float*)w_proj, wprojT, 1024, 1024);

    // t3: proj GEMM -> fp32 out (overwrites abf scratch; reads only ws)
    gemm_bt<0, float><<<dim3(1024 / 128, 8192 / 128), 256, 0, stream>>>(
        ob, wprojT, (const float*)b_proj, out, nullptr, nullptr, nullptr,
        8192, 1024, 1024);
}